// Round 9
// baseline (175.615 us; speedup 1.0000x reference)
//
#include <hip/hip_runtime.h>

typedef __attribute__((ext_vector_type(8))) __bf16 bf16x8;
typedef __attribute__((ext_vector_type(4))) float f32x4;

#define MAX_ITER_N 20
#define F_TOL_F 1e-6f
#define FREE_NUM_N 64

#define BSZ 1024
#define IN_DIM 512
#define HID 1024
#define OUT_DIM 256
#define M_CON 128

// workspace layout (float offsets)
#define WS_BAR   0                          // 2 uints
#define WS_RES   8                          // 32 uints
#define WS_BP    48                         // 256 f32
#define WS_H1    304                        // 1024x1024 bf16 = 524288 floats
#define WS_H2    (WS_H1 + 524288)           // 1024x1024 bf16
#define WS_WZG   (WS_H2 + 524288)           // 256x256 bf16 = 32768 floats
#define WS_AG    (WS_WZG + 32768)           // 128x256 bf16 = 16384 floats
#define WS_P0    (WS_AG + 16384)            // 2 x 1024x256 f32 split-K partials

__device__ __forceinline__ unsigned short f2bf(float f) {
    unsigned int u = __float_as_uint(f);
    u += 0x7fffu + ((u >> 16) & 1u);
    return (unsigned short)(u >> 16);
}

__device__ __forceinline__ uint4 cvt8(float4 a, float4 b) {
    union { unsigned short s[8]; uint4 v; } u;
    u.s[0] = f2bf(a.x); u.s[1] = f2bf(a.y); u.s[2] = f2bf(a.z); u.s[3] = f2bf(a.w);
    u.s[4] = f2bf(b.x); u.s[5] = f2bf(b.y); u.s[6] = f2bf(b.z); u.s[7] = f2bf(b.w);
    return u.v;
}

__device__ __forceinline__ void gload_lds16(const unsigned short* g, unsigned short* l) {
    __builtin_amdgcn_global_load_lds(
        (const __attribute__((address_space(1))) unsigned int*)(const void*)g,
        (__attribute__((address_space(3))) unsigned int*)(void*)l, 16, 0, 0);
}

__device__ __forceinline__ bf16x8 ldfrag(const unsigned short* p) {
    return __builtin_bit_cast(bf16x8, *(const uint4*)p);
}

// fragment read from a 32x128 bf16 tile with 4-bit XOR granule swizzle
__device__ __forceinline__ bf16x8 frag128(const unsigned short* lds, int row, int gc) {
    int phys = gc ^ (row & 15);
    return __builtin_bit_cast(bf16x8, *(const uint4*)(lds + row * 128 + phys * 8));
}

// device-scope grid barrier (nblk blocks co-resident by capacity)
__device__ __forceinline__ void grid_barrier(unsigned int* bar, unsigned int nblk) {
    __syncthreads();
    if (threadIdx.x == 0) {
        unsigned int g = __hip_atomic_load(&bar[1], __ATOMIC_RELAXED, __HIP_MEMORY_SCOPE_AGENT);
        unsigned int a = __hip_atomic_fetch_add(&bar[0], 1u, __ATOMIC_ACQ_REL, __HIP_MEMORY_SCOPE_AGENT);
        if (a == nblk - 1u) {
            __hip_atomic_store(&bar[0], 0u, __ATOMIC_RELAXED, __HIP_MEMORY_SCOPE_AGENT);
            __hip_atomic_store(&bar[1], g + 1u, __ATOMIC_RELEASE, __HIP_MEMORY_SCOPE_AGENT);
        } else {
            while (__hip_atomic_load(&bar[1], __ATOMIC_ACQUIRE, __HIP_MEMORY_SCOPE_AGENT) == g)
                __builtin_amdgcn_s_sleep(2);
        }
    }
    __syncthreads();
}

// ---- 32x32-tile MFMA GEMM, K-extent Kext (chunked by 128), strides ldA/ldB;
// double-buffered; f32 operands converted during staging. OUTMODE: 0=bf16(+bias,
// +relu per flag), 1=f32 partial (no bias) ----
template<int Kext, bool AF32, bool BF32, bool RELU, int OUTMODE>
__device__ __forceinline__ void gemm32_dev(
    const void* __restrict__ Av, const void* __restrict__ Bv,
    const float* __restrict__ bias, void* __restrict__ Cv, int N_,
    int ldA, int ldB, int tile, int NTN,
    unsigned short (*As)[32 * 128], unsigned short (*Bs)[32 * 128])
{
    constexpr int NCH = Kext / 128;
    const int tid = threadIdx.x;
    const int w = tid >> 6;
    const int lane = tid & 63;
    const int ln = lane & 15;
    const int q  = lane >> 4;
    const int wr = w >> 1;
    const int wc = w & 1;
    const int row0 = (tile / NTN) * 32;
    const int col0 = (tile % NTN) * 32;

    int goffA[2], goffB[2], lgran[2], soffA[2], soffB[2], dbase[2];
#pragma unroll
    for (int i = 0; i < 2; ++i) {
        int P = i * 256 + tid;
        int row = P >> 4, gc = P & 15;
        goffA[i] = row * ldA + gc * 8;                  // f32 source (elems)
        goffB[i] = row * ldB + gc * 8;
        lgran[i] = row * 128 + (gc ^ (row & 15)) * 8;   // swizzled LDS dest (shorts)
        int base = w * 128 + i * 64;                    // wave-uniform granule base
        int P2 = base + lane;
        int row2 = P2 >> 4, pgc = (P2 & 15) ^ (row2 & 15);
        soffA[i] = row2 * ldA + pgc * 8;                // XOR-permuted global source
        soffB[i] = row2 * ldB + pgc * 8;
        dbase[i] = base * 8;
    }

    const float* Af = (const float*)Av;
    const float* Bf = (const float*)Bv;
    const unsigned short* Ah = (const unsigned short*)Av;
    const unsigned short* Bh = (const unsigned short*)Bv;

    float4 fa[2][2], fb[2][2];
    // prologue: chunk 0 -> buffer 0
    if constexpr (AF32) {
#pragma unroll
        for (int i = 0; i < 2; ++i) {
            fa[i][0] = *(const float4*)(Af + goffA[i]);
            fa[i][1] = *(const float4*)(Af + goffA[i] + 4);
        }
#pragma unroll
        for (int i = 0; i < 2; ++i) *(uint4*)&As[0][lgran[i]] = cvt8(fa[i][0], fa[i][1]);
    } else {
#pragma unroll
        for (int i = 0; i < 2; ++i) gload_lds16(Ah + soffA[i], &As[0][dbase[i]]);
    }
    if constexpr (BF32) {
#pragma unroll
        for (int i = 0; i < 2; ++i) {
            fb[i][0] = *(const float4*)(Bf + goffB[i]);
            fb[i][1] = *(const float4*)(Bf + goffB[i] + 4);
        }
#pragma unroll
        for (int i = 0; i < 2; ++i) *(uint4*)&Bs[0][lgran[i]] = cvt8(fb[i][0], fb[i][1]);
    } else {
#pragma unroll
        for (int i = 0; i < 2; ++i) gload_lds16(Bh + soffB[i], &Bs[0][dbase[i]]);
    }

    f32x4 acc = {0.f, 0.f, 0.f, 0.f};

    for (int c = 0; c < NCH; ++c) {
        __syncthreads();                    // buf[c&1] complete (vm+lgkm drained)
        const int nb = (c + 1) & 1;
        if (c + 1 < NCH) {                  // issue next-chunk loads (no use yet)
            if constexpr (AF32) {
#pragma unroll
                for (int i = 0; i < 2; ++i) {
                    fa[i][0] = *(const float4*)(Af + (c + 1) * 128 + goffA[i]);
                    fa[i][1] = *(const float4*)(Af + (c + 1) * 128 + goffA[i] + 4);
                }
            } else {
#pragma unroll
                for (int i = 0; i < 2; ++i)
                    gload_lds16(Ah + (c + 1) * 128 + soffA[i], &As[nb][dbase[i]]);
            }
            if constexpr (BF32) {
#pragma unroll
                for (int i = 0; i < 2; ++i) {
                    fb[i][0] = *(const float4*)(Bf + (c + 1) * 128 + goffB[i]);
                    fb[i][1] = *(const float4*)(Bf + (c + 1) * 128 + goffB[i] + 4);
                }
            } else {
#pragma unroll
                for (int i = 0; i < 2; ++i)
                    gload_lds16(Bh + (c + 1) * 128 + soffB[i], &Bs[nb][dbase[i]]);
            }
        }
        const unsigned short* Ac = As[c & 1];
        const unsigned short* Bc = Bs[c & 1];
#pragma unroll
        for (int ks = 0; ks < 4; ++ks) {
            bf16x8 af = frag128(Ac, wr * 16 + ln, ks * 4 + q);
            bf16x8 bf = frag128(Bc, wc * 16 + ln, ks * 4 + q);
            acc = __builtin_amdgcn_mfma_f32_16x16x32_bf16(af, bf, acc, 0, 0, 0);
        }
        if (c + 1 < NCH) {                  // commit converted data to next buffer
            if constexpr (AF32) {
#pragma unroll
                for (int i = 0; i < 2; ++i) *(uint4*)&As[nb][lgran[i]] = cvt8(fa[i][0], fa[i][1]);
            }
            if constexpr (BF32) {
#pragma unroll
                for (int i = 0; i < 2; ++i) *(uint4*)&Bs[nb][lgran[i]] = cvt8(fb[i][0], fb[i][1]);
            }
        }
    }

    const int cc = col0 + wc * 16 + ln;
    if constexpr (OUTMODE == 0) {
        const float bv = bias[cc];
#pragma unroll
        for (int i = 0; i < 4; ++i) {
            int r = row0 + wr * 16 + q * 4 + i;
            float v = acc[i] + bv;
            if (RELU) v = fmaxf(v, 0.0f);
            ((unsigned short*)Cv)[r * N_ + cc] = f2bf(v);
        }
    } else {
#pragma unroll
        for (int i = 0; i < 4; ++i) {
            int r = row0 + wr * 16 + q * 4 + i;
            ((float*)Cv)[r * N_ + cc] = acc[i];
        }
    }
}

// ---- K1: h1 = relu(b_primal @ W0^T + b0); converts both operands on the fly ----
__global__ __launch_bounds__(256, 5) void g1_k(
    const float* __restrict__ b_primal, const float* __restrict__ W0,
    const float* __restrict__ b0, float* __restrict__ ws)
{
    __shared__ __align__(16) unsigned short As[2][32 * 128];
    __shared__ __align__(16) unsigned short Bs[2][32 * 128];
    if (blockIdx.x == 0 && threadIdx.x < 40)
        ((unsigned int*)ws)[threadIdx.x] = 0u;      // zero bar + res slots
    unsigned short* h1c = (unsigned short*)(ws + WS_H1);
    const int tile = blockIdx.x;
    const float* Ab = b_primal + (tile / 32) * 32 * IN_DIM;
    const float* Bb = W0 + (tile % 32) * 32 * IN_DIM;
    gemm32_dev<IN_DIM, true, true, true, 0>(Ab, Bb, b0, h1c, HID,
                                            IN_DIM, IN_DIM, tile, 32, As, Bs);
}

// ---- K2: h2 = relu(h1 @ W1^T + b1); blocks >=1024 convert Wz/A + bias_proj ----
__global__ __launch_bounds__(256, 5) void g2_k(
    const float* __restrict__ W1, const float* __restrict__ b1,
    const float* __restrict__ Wz, const float* __restrict__ Amat,
    const float* __restrict__ b_vec, const float* __restrict__ WbProj,
    float* __restrict__ ws)
{
    __shared__ __align__(16) unsigned short As[2][32 * 128];
    __shared__ __align__(16) unsigned short Bs[2][32 * 128];
    const int tid = threadIdx.x;
    if (blockIdx.x >= 1024) {
        int b = blockIdx.x - 1024;
        if (b == 96) {                                // bias_proj (f32, exact)
            float s = 0.0f;
            const float* wrow = WbProj + tid * M_CON;
            for (int k = 0; k < M_CON; ++k) s += b_vec[k] * wrow[k];
            (ws + WS_BP)[tid] = s;
            return;
        }
        const float* src; unsigned short* dst; int off;
        if (b < 64) { src = Wz;   dst = (unsigned short*)(ws + WS_WZG); off = b; }
        else        { src = Amat; dst = (unsigned short*)(ws + WS_AG);  off = b - 64; }
        int idx = off * 1024 + tid * 4;
        float4 v = *(const float4*)(src + idx);
        ushort4 o;
        o.x = f2bf(v.x); o.y = f2bf(v.y); o.z = f2bf(v.z); o.w = f2bf(v.w);
        *(ushort4*)(dst + idx) = o;
        return;
    }
    const unsigned short* h1c = (const unsigned short*)(ws + WS_H1);
    unsigned short* h2c = (unsigned short*)(ws + WS_H2);
    const int tile = blockIdx.x;
    const unsigned short* Ab = h1c + (tile / 32) * 32 * HID;
    const float* Bb = W1 + (tile % 32) * 32 * HID;
    gemm32_dev<HID, false, true, true, 0>(Ab, Bb, b1, h2c, HID,
                                          HID, HID, tile, 32, As, Bs);
}

// ---- K3: split-K x2 partials of h2 @ W2^T (no bias); 512 blocks, 2/CU ----
__global__ __launch_bounds__(256, 4) void g3_k(
    const float* __restrict__ W2, float* __restrict__ ws)
{
    __shared__ __align__(16) unsigned short As[2][32 * 128];
    __shared__ __align__(16) unsigned short Bs[2][32 * 128];
    const unsigned short* h2c = (const unsigned short*)(ws + WS_H2);
    const int tile = blockIdx.x & 255;
    const int half = blockIdx.x >> 8;
    float* part = ws + WS_P0 + half * (BSZ * OUT_DIM);
    const unsigned short* Ab = h2c + (tile / 8) * 32 * HID + half * 512;
    const float* Bb = W2 + (tile % 8) * 32 * HID + half * 512;
    gemm32_dev<512, false, true, false, 1>(Ab, Bb, nullptr, part, OUT_DIM,
                                           HID, HID, tile, 8, As, Bs);
}

// ---- K4: z0-assemble + 20-iter fixed point + decide + cold fallback; 64 blocks ----
__global__ __launch_bounds__(256, 1) void loop_k(
    const float* __restrict__ b2, const float* __restrict__ b_vec,
    const float* __restrict__ WzProj, float* __restrict__ out,
    float* __restrict__ ws)
{
    __shared__ __align__(16) unsigned char smem[16 * 257 * 4 + 64];
    unsigned int* bar = (unsigned int*)(ws + WS_BAR);
    unsigned int* res = (unsigned int*)(ws + WS_RES);
    const float* bp = ws + WS_BP;
    const unsigned short* WzG = (const unsigned short*)(ws + WS_WZG);
    const unsigned short* AG  = (const unsigned short*)(ws + WS_AG);
    const float* p0 = ws + WS_P0;
    const float* p1 = ws + WS_P0 + BSZ * OUT_DIM;
    float* outz = out + BSZ * OUT_DIM;

    const int tid  = threadIdx.x;
    const int wave = tid >> 6;
    const int lane = tid & 63;
    const int ln   = lane & 15;
    const int q    = lane >> 4;
    const int r0   = blockIdx.x * 16;

    unsigned short (*zS)[264] = (unsigned short(*)[264])smem;

    // phase 0: z0 = p0 + p1 + b2 -> outz (f32 MLP output) + zS (bf16)
    {
        int row = tid >> 4;
        int c0  = (tid & 15) * 16;
        int base = (r0 + row) * OUT_DIM + c0;
#pragma unroll
        for (int v4 = 0; v4 < 4; ++v4) {
            float4 a = *(const float4*)(p0 + base + v4 * 4);
            float4 b = *(const float4*)(p1 + base + v4 * 4);
            float4 bb = *(const float4*)(b2 + c0 + v4 * 4);
            float4 o;
            o.x = a.x + b.x + bb.x; o.y = a.y + b.y + bb.y;
            o.z = a.z + b.z + bb.z; o.w = a.w + b.w + bb.w;
            *(float4*)(outz + base + v4 * 4) = o;
            zS[row][c0 + v4 * 4 + 0] = f2bf(o.x);
            zS[row][c0 + v4 * 4 + 1] = f2bf(o.y);
            zS[row][c0 + v4 * 4 + 2] = f2bf(o.z);
            zS[row][c0 + v4 * 4 + 3] = f2bf(o.w);
        }
    }

    bf16x8 afr[2][8];
    float bvv[2];
#pragma unroll
    for (int mt = 0; mt < 2; ++mt) {
        int m = wave * 32 + mt * 16 + ln;
        bvv[mt] = b_vec[m];
#pragma unroll
        for (int ks = 0; ks < 8; ++ks)
            afr[mt][ks] = ldfrag(AG + m * OUT_DIM + ks * 32 + q * 8);
    }
    int colg[4];
    float bpv[4];
    bf16x8 wzfr[4][8];
#pragma unroll
    for (int nt = 0; nt < 4; ++nt) {
        colg[nt] = wave * 64 + nt * 16 + ln;
        bpv[nt]  = bp[colg[nt]];
#pragma unroll
        for (int ks = 0; ks < 8; ++ks)
            wzfr[nt][ks] = ldfrag(WzG + colg[nt] * OUT_DIM + ks * 32 + q * 8);
    }
    __syncthreads();

    bf16x8 zfr[8];
#pragma unroll
    for (int ks = 0; ks < 8; ++ks)
        zfr[ks] = __builtin_bit_cast(bf16x8, *(const uint4*)&zS[ln][ks * 32 + q * 8]);

    const f32x4 zero4 = {0.f, 0.f, 0.f, 0.f};

    for (int t = 1; t <= MAX_ITER_N; ++t) {
        // z-update: two 4-deep partial chains per column tile
        f32x4 accA[4], accB[4];
#pragma unroll
        for (int nt = 0; nt < 4; ++nt) { accA[nt] = zero4; accB[nt] = zero4; }
#pragma unroll
        for (int ks = 0; ks < 4; ++ks)
#pragma unroll
            for (int nt = 0; nt < 4; ++nt) {
                accA[nt] = __builtin_amdgcn_mfma_f32_16x16x32_bf16(zfr[ks], wzfr[nt][ks], accA[nt], 0, 0, 0);
                accB[nt] = __builtin_amdgcn_mfma_f32_16x16x32_bf16(zfr[ks + 4], wzfr[nt][ks + 4], accB[nt], 0, 0, 0);
            }
        float vals[4][4];
#pragma unroll
        for (int nt = 0; nt < 4; ++nt)
#pragma unroll
            for (int i = 0; i < 4; ++i) {
                float v = accA[nt][i] + accB[nt][i] + bpv[nt];
                if (colg[nt] >= FREE_NUM_N) v = fmaxf(v, 0.0f);
                vals[nt][i] = v;
            }
        if (t == MAX_ITER_N) {
#pragma unroll
            for (int nt = 0; nt < 4; ++nt)
#pragma unroll
                for (int i = 0; i < 4; ++i)
                    out[(r0 + q * 4 + i) * OUT_DIM + colg[nt]] = vals[nt][i];
        }
        __syncthreads();   // S1: all waves done reading zS (z_{t-1})
#pragma unroll
        for (int nt = 0; nt < 4; ++nt)
#pragma unroll
            for (int i = 0; i < 4; ++i)
                zS[q * 4 + i][colg[nt]] = f2bf(vals[nt][i]);
        __syncthreads();   // S2: zS = z_t complete
#pragma unroll
        for (int ks = 0; ks < 8; ++ks)
            zfr[ks] = __builtin_bit_cast(bf16x8, *(const uint4*)&zS[ln][ks * 32 + q * 8]);

        // residual: two 4-deep partial chains per m tile; per-wave atomic (no barrier)
        f32x4 r2A[2], r2B[2];
        r2A[0] = zero4; r2A[1] = zero4; r2B[0] = zero4; r2B[1] = zero4;
#pragma unroll
        for (int ks = 0; ks < 4; ++ks)
#pragma unroll
            for (int mt = 0; mt < 2; ++mt) {
                r2A[mt] = __builtin_amdgcn_mfma_f32_16x16x32_bf16(zfr[ks], afr[mt][ks], r2A[mt], 0, 0, 0);
                r2B[mt] = __builtin_amdgcn_mfma_f32_16x16x32_bf16(zfr[ks + 4], afr[mt][ks + 4], r2B[mt], 0, 0, 0);
            }
        float lmax = 0.0f;
#pragma unroll
        for (int mt = 0; mt < 2; ++mt)
#pragma unroll
            for (int i = 0; i < 4; ++i)
                lmax = fmaxf(lmax, fabsf(r2A[mt][i] + r2B[mt][i] - bvv[mt]));
#pragma unroll
        for (int off = 32; off > 0; off >>= 1)
            lmax = fmaxf(lmax, __shfl_xor(lmax, off));
        if (lane == 0)
            atomicMax(res + (t - 1), __float_as_uint(lmax));   // fire-and-forget
    }

    grid_barrier(bar, 64);   // 64 blocks <= 256 CUs: co-residency guaranteed

    // decide (replay reference stopping rule) + cold fp32 fallback
    int T = MAX_ITER_N;
    for (int t = 0; t < MAX_ITER_N; ++t) {
        float r = __uint_as_float(res[t]);
        if (!(r > F_TOL_F)) { T = t + 1; break; }   // covers res<=tol and NaN
    }
    if (blockIdx.x == 0 && tid == 0)
        out[2 * BSZ * OUT_DIM] = (float)(T + 1);    // curr_iter

    if (T < MAX_ITER_N) {                           // cold path: exact fp32 recompute
        float (*zF)[257] = (float(*)[257])smem;
        const int row = tid >> 4;
        const int c0 = (tid & 15) * 16;
        __syncthreads();
        for (int i = 0; i < 16; ++i) zF[row][c0 + i] = outz[(r0 + row) * OUT_DIM + c0 + i];
        __syncthreads();
        const int j = tid;
        const float bj = bp[j];
        for (int t = 0; t < T; ++t) {
            float acc[16] = {};
            for (int k = 0; k < OUT_DIM; ++k) {
                float w = WzProj[j * OUT_DIM + k];
#pragma unroll
                for (int r = 0; r < 16; ++r) acc[r] += zF[r][k] * w;
            }
            __syncthreads();
#pragma unroll
            for (int r = 0; r < 16; ++r) {
                float v = acc[r] + bj;
                if (j >= FREE_NUM_N) v = fmaxf(v, 0.0f);
                zF[r][j] = v;
            }
            __syncthreads();
        }
        for (int i = 0; i < 16; ++i) out[(r0 + row) * OUT_DIM + c0 + i] = zF[row][c0 + i];
    }
}

extern "C" void kernel_launch(void* const* d_in, const int* in_sizes, int n_in,
                              void* d_out, int out_size, void* d_ws, size_t ws_size,
                              hipStream_t stream) {
    const float* b_primal = (const float*)d_in[0];
    const float* W0     = (const float*)d_in[1];
    const float* b0     = (const float*)d_in[2];
    const float* W1     = (const float*)d_in[3];
    const float* b1     = (const float*)d_in[4];
    const float* W2     = (const float*)d_in[5];
    const float* b2     = (const float*)d_in[6];
    const float* Amat   = (const float*)d_in[7];
    const float* b_vec  = (const float*)d_in[8];
    const float* WzProj = (const float*)d_in[9];
    const float* WbProj = (const float*)d_in[10];
    float* out = (float*)d_out;
    float* ws  = (float*)d_ws;

    hipLaunchKernelGGL(g1_k, dim3(1024), dim3(256), 0, stream,
                       b_primal, W0, b0, ws);
    hipLaunchKernelGGL(g2_k, dim3(1024 + 97), dim3(256), 0, stream,
                       W1, b1, WzProj, Amat, b_vec, WbProj, ws);
    hipLaunchKernelGGL(g3_k, dim3(512), dim3(256), 0, stream,
                       W2, ws);
    hipLaunchKernelGGL(loop_k, dim3(64), dim3(256), 0, stream,
                       b2, b_vec, WzProj, out, ws);
}

// Round 10
// 141.447 us; speedup vs baseline: 1.2416x; 1.2416x over previous
//
#include <hip/hip_runtime.h>

typedef __attribute__((ext_vector_type(8))) __bf16 bf16x8;
typedef __attribute__((ext_vector_type(4))) float f32x4;

#define MAX_ITER_N 20
#define F_TOL_F 1e-6f
#define FREE_NUM_N 64

#define BSZ 1024
#define IN_DIM 512
#define HID 1024
#define OUT_DIM 256
#define M_CON 128

// workspace layout (float offsets)
#define WS_BAR   0                          // 2 uints
#define WS_RES   8                          // 32 uints
#define WS_BP    48                         // 256 f32
#define WS_H1    304                        // 1024x1024 bf16 = 524288 floats
#define WS_H2    (WS_H1 + 524288)           // 1024x1024 bf16
#define WS_WZG   (WS_H2 + 524288)           // 256x256 bf16 = 32768 floats
#define WS_AG    (WS_WZG + 32768)           // 128x256 bf16 = 16384 floats

__device__ __forceinline__ unsigned short f2bf(float f) {
    unsigned int u = __float_as_uint(f);
    u += 0x7fffu + ((u >> 16) & 1u);
    return (unsigned short)(u >> 16);
}

__device__ __forceinline__ uint4 cvt8(float4 a, float4 b) {
    union { unsigned short s[8]; uint4 v; } u;
    u.s[0] = f2bf(a.x); u.s[1] = f2bf(a.y); u.s[2] = f2bf(a.z); u.s[3] = f2bf(a.w);
    u.s[4] = f2bf(b.x); u.s[5] = f2bf(b.y); u.s[6] = f2bf(b.z); u.s[7] = f2bf(b.w);
    return u.v;
}

__device__ __forceinline__ void gload_lds16(const unsigned short* g, unsigned short* l) {
    __builtin_amdgcn_global_load_lds(
        (const __attribute__((address_space(1))) unsigned int*)(const void*)g,
        (__attribute__((address_space(3))) unsigned int*)(void*)l, 16, 0, 0);
}

__device__ __forceinline__ bf16x8 ldfrag(const unsigned short* p) {
    return __builtin_bit_cast(bf16x8, *(const uint4*)p);
}

// fragment read from a 32x128 bf16 tile with 4-bit XOR granule swizzle
__device__ __forceinline__ bf16x8 frag128(const unsigned short* lds, int row, int gc) {
    int phys = gc ^ (row & 15);
    return __builtin_bit_cast(bf16x8, *(const uint4*)(lds + row * 128 + phys * 8));
}

// device-scope grid barrier (nblk blocks co-resident by capacity)
__device__ __forceinline__ void grid_barrier(unsigned int* bar, unsigned int nblk) {
    __syncthreads();
    if (threadIdx.x == 0) {
        unsigned int g = __hip_atomic_load(&bar[1], __ATOMIC_RELAXED, __HIP_MEMORY_SCOPE_AGENT);
        unsigned int a = __hip_atomic_fetch_add(&bar[0], 1u, __ATOMIC_ACQ_REL, __HIP_MEMORY_SCOPE_AGENT);
        if (a == nblk - 1u) {
            __hip_atomic_store(&bar[0], 0u, __ATOMIC_RELAXED, __HIP_MEMORY_SCOPE_AGENT);
            __hip_atomic_store(&bar[1], g + 1u, __ATOMIC_RELEASE, __HIP_MEMORY_SCOPE_AGENT);
        } else {
            while (__hip_atomic_load(&bar[1], __ATOMIC_ACQUIRE, __HIP_MEMORY_SCOPE_AGENT) == g)
                __builtin_amdgcn_s_sleep(2);
        }
    }
    __syncthreads();
}

// ---- 32x32-tile MFMA GEMM, BK=128, double-buffered; f32 operands converted
// during staging. OUTMODE: 0 = bf16 out (+bias, +relu per flag), 1 = f32 out (+bias) ----
template<int Kext, bool AF32, bool BF32, bool RELU, int OUTMODE>
__device__ __forceinline__ void gemm32_dev(
    const void* __restrict__ Av, const void* __restrict__ Bv,
    const float* __restrict__ bias, void* __restrict__ Cv, int N_,
    int ldA, int ldB, int tile, int NTN,
    unsigned short (*As)[32 * 128], unsigned short (*Bs)[32 * 128])
{
    constexpr int NCH = Kext / 128;
    const int tid = threadIdx.x;
    const int w = tid >> 6;
    const int lane = tid & 63;
    const int ln = lane & 15;
    const int q  = lane >> 4;
    const int wr = w >> 1;
    const int wc = w & 1;
    const int row0 = (tile / NTN) * 32;
    const int col0 = (tile % NTN) * 32;

    int goffA[2], goffB[2], lgran[2], soffA[2], soffB[2], dbase[2];
#pragma unroll
    for (int i = 0; i < 2; ++i) {
        int P = i * 256 + tid;
        int row = P >> 4, gc = P & 15;
        goffA[i] = row * ldA + gc * 8;
        goffB[i] = row * ldB + gc * 8;
        lgran[i] = row * 128 + (gc ^ (row & 15)) * 8;
        int base = w * 128 + i * 64;
        int P2 = base + lane;
        int row2 = P2 >> 4, pgc = (P2 & 15) ^ (row2 & 15);
        soffA[i] = row2 * ldA + pgc * 8;
        soffB[i] = row2 * ldB + pgc * 8;
        dbase[i] = base * 8;
    }

    const float* Af = (const float*)Av;
    const float* Bf = (const float*)Bv;
    const unsigned short* Ah = (const unsigned short*)Av;
    const unsigned short* Bh = (const unsigned short*)Bv;

    float4 fa[2][2], fb[2][2];
    if constexpr (AF32) {
#pragma unroll
        for (int i = 0; i < 2; ++i) {
            fa[i][0] = *(const float4*)(Af + goffA[i]);
            fa[i][1] = *(const float4*)(Af + goffA[i] + 4);
        }
#pragma unroll
        for (int i = 0; i < 2; ++i) *(uint4*)&As[0][lgran[i]] = cvt8(fa[i][0], fa[i][1]);
    } else {
#pragma unroll
        for (int i = 0; i < 2; ++i) gload_lds16(Ah + soffA[i], &As[0][dbase[i]]);
    }
    if constexpr (BF32) {
#pragma unroll
        for (int i = 0; i < 2; ++i) {
            fb[i][0] = *(const float4*)(Bf + goffB[i]);
            fb[i][1] = *(const float4*)(Bf + goffB[i] + 4);
        }
#pragma unroll
        for (int i = 0; i < 2; ++i) *(uint4*)&Bs[0][lgran[i]] = cvt8(fb[i][0], fb[i][1]);
    } else {
#pragma unroll
        for (int i = 0; i < 2; ++i) gload_lds16(Bh + soffB[i], &Bs[0][dbase[i]]);
    }

    f32x4 acc = {0.f, 0.f, 0.f, 0.f};

    for (int c = 0; c < NCH; ++c) {
        __syncthreads();
        const int nb = (c + 1) & 1;
        if (c + 1 < NCH) {
            if constexpr (AF32) {
#pragma unroll
                for (int i = 0; i < 2; ++i) {
                    fa[i][0] = *(const float4*)(Af + (c + 1) * 128 + goffA[i]);
                    fa[i][1] = *(const float4*)(Af + (c + 1) * 128 + goffA[i] + 4);
                }
            } else {
#pragma unroll
                for (int i = 0; i < 2; ++i)
                    gload_lds16(Ah + (c + 1) * 128 + soffA[i], &As[nb][dbase[i]]);
            }
            if constexpr (BF32) {
#pragma unroll
                for (int i = 0; i < 2; ++i) {
                    fb[i][0] = *(const float4*)(Bf + (c + 1) * 128 + goffB[i]);
                    fb[i][1] = *(const float4*)(Bf + (c + 1) * 128 + goffB[i] + 4);
                }
            } else {
#pragma unroll
                for (int i = 0; i < 2; ++i)
                    gload_lds16(Bh + (c + 1) * 128 + soffB[i], &Bs[nb][dbase[i]]);
            }
        }
        const unsigned short* Ac = As[c & 1];
        const unsigned short* Bc = Bs[c & 1];
#pragma unroll
        for (int ks = 0; ks < 4; ++ks) {
            bf16x8 af = frag128(Ac, wr * 16 + ln, ks * 4 + q);
            bf16x8 bf = frag128(Bc, wc * 16 + ln, ks * 4 + q);
            acc = __builtin_amdgcn_mfma_f32_16x16x32_bf16(af, bf, acc, 0, 0, 0);
        }
        if (c + 1 < NCH) {
            if constexpr (AF32) {
#pragma unroll
                for (int i = 0; i < 2; ++i) *(uint4*)&As[nb][lgran[i]] = cvt8(fa[i][0], fa[i][1]);
            }
            if constexpr (BF32) {
#pragma unroll
                for (int i = 0; i < 2; ++i) *(uint4*)&Bs[nb][lgran[i]] = cvt8(fb[i][0], fb[i][1]);
            }
        }
    }

    const int cc = col0 + wc * 16 + ln;
    const float bv = bias[cc];
#pragma unroll
    for (int i = 0; i < 4; ++i) {
        int r = row0 + wr * 16 + q * 4 + i;
        float v = acc[i] + bv;
        if (RELU) v = fmaxf(v, 0.0f);
        if (OUTMODE == 1) ((float*)Cv)[r * N_ + cc] = v;
        else ((unsigned short*)Cv)[r * N_ + cc] = f2bf(v);
    }
}

// ---- K1: h1 = relu(b_primal @ W0^T + b0) ----
__global__ __launch_bounds__(256, 5) void g1_k(
    const float* __restrict__ b_primal, const float* __restrict__ W0,
    const float* __restrict__ b0, float* __restrict__ ws)
{
    __shared__ __align__(16) unsigned short As[2][32 * 128];
    __shared__ __align__(16) unsigned short Bs[2][32 * 128];
    if (blockIdx.x == 0 && threadIdx.x < 40)
        ((unsigned int*)ws)[threadIdx.x] = 0u;      // zero bar + res slots
    unsigned short* h1c = (unsigned short*)(ws + WS_H1);
    const int tile = blockIdx.x;
    const float* Ab = b_primal + (tile / 32) * 32 * IN_DIM;
    const float* Bb = W0 + (tile % 32) * 32 * IN_DIM;
    gemm32_dev<IN_DIM, true, true, true, 0>(Ab, Bb, b0, h1c, HID,
                                            IN_DIM, IN_DIM, tile, 32, As, Bs);
}

// ---- K2: h2 = relu(h1 @ W1^T + b1); blocks >=1024 convert Wz/A + bias_proj ----
__global__ __launch_bounds__(256, 5) void g2_k(
    const float* __restrict__ W1, const float* __restrict__ b1,
    const float* __restrict__ Wz, const float* __restrict__ Amat,
    const float* __restrict__ b_vec, const float* __restrict__ WbProj,
    float* __restrict__ ws)
{
    __shared__ __align__(16) unsigned short As[2][32 * 128];
    __shared__ __align__(16) unsigned short Bs[2][32 * 128];
    const int tid = threadIdx.x;
    if (blockIdx.x >= 1024) {
        int b = blockIdx.x - 1024;
        if (b == 96) {                                // bias_proj (f32, exact)
            float s = 0.0f;
            const float* wrow = WbProj + tid * M_CON;
            for (int k = 0; k < M_CON; ++k) s += b_vec[k] * wrow[k];
            (ws + WS_BP)[tid] = s;
            return;
        }
        const float* src; unsigned short* dst; int off;
        if (b < 64) { src = Wz;   dst = (unsigned short*)(ws + WS_WZG); off = b; }
        else        { src = Amat; dst = (unsigned short*)(ws + WS_AG);  off = b - 64; }
        int idx = off * 1024 + tid * 4;
        float4 v = *(const float4*)(src + idx);
        ushort4 o;
        o.x = f2bf(v.x); o.y = f2bf(v.y); o.z = f2bf(v.z); o.w = f2bf(v.w);
        *(ushort4*)(dst + idx) = o;
        return;
    }
    const unsigned short* h1c = (const unsigned short*)(ws + WS_H1);
    unsigned short* h2c = (unsigned short*)(ws + WS_H2);
    const int tile = blockIdx.x;
    const unsigned short* Ab = h1c + (tile / 32) * 32 * HID;
    const float* Bb = W1 + (tile % 32) * 32 * HID;
    gemm32_dev<HID, false, true, true, 0>(Ab, Bb, b1, h2c, HID,
                                          HID, HID, tile, 32, As, Bs);
}

// ---- K3: out-MLP = h2 @ W2^T + b2 (f32 out, W2 converted on the fly) ----
__global__ __launch_bounds__(256, 4) void g3_k(
    const float* __restrict__ W2, const float* __restrict__ b2,
    float* __restrict__ out, float* __restrict__ ws)
{
    __shared__ __align__(16) unsigned short As[2][32 * 128];
    __shared__ __align__(16) unsigned short Bs[2][32 * 128];
    const unsigned short* h2c = (const unsigned short*)(ws + WS_H2);
    float* outz = out + BSZ * OUT_DIM;
    const int tile = blockIdx.x;
    const unsigned short* Ab = h2c + (tile / 8) * 32 * HID;
    const float* Bb = W2 + (tile % 8) * 32 * HID;
    gemm32_dev<HID, false, true, false, 1>(Ab, Bb, b2, outz, OUT_DIM,
                                           HID, HID, tile, 8, As, Bs);
}

// ---- K4: 20-iter fixed point (no global traffic in loop) + decide + fallback ----
__global__ __launch_bounds__(256, 1) void loop_k(
    const float* __restrict__ b_vec, const float* __restrict__ WzProj,
    float* __restrict__ out, float* __restrict__ ws)
{
    __shared__ __align__(16) unsigned char smem[16 * 257 * 4 + 64];
    __shared__ float resS[MAX_ITER_N][4];   // per-iteration, per-wave residual max
    unsigned int* bar = (unsigned int*)(ws + WS_BAR);
    unsigned int* res = (unsigned int*)(ws + WS_RES);
    const float* bp = ws + WS_BP;
    const unsigned short* WzG = (const unsigned short*)(ws + WS_WZG);
    const unsigned short* AG  = (const unsigned short*)(ws + WS_AG);
    float* outz = out + BSZ * OUT_DIM;

    const int tid  = threadIdx.x;
    const int wave = tid >> 6;
    const int lane = tid & 63;
    const int ln   = lane & 15;
    const int q    = lane >> 4;
    const int r0   = blockIdx.x * 16;

    unsigned short (*zS)[264] = (unsigned short(*)[264])smem;

    {
        int row = tid >> 4;
        int c0  = (tid & 15) * 16;
        const float* src = outz + (r0 + row) * OUT_DIM + c0;
#pragma unroll
        for (int i = 0; i < 16; ++i) zS[row][c0 + i] = f2bf(src[i]);
    }

    bf16x8 afr[2][8];
    float bvv[2];
#pragma unroll
    for (int mt = 0; mt < 2; ++mt) {
        int m = wave * 32 + mt * 16 + ln;
        bvv[mt] = b_vec[m];
#pragma unroll
        for (int ks = 0; ks < 8; ++ks)
            afr[mt][ks] = ldfrag(AG + m * OUT_DIM + ks * 32 + q * 8);
    }
    int colg[4];
    float bpv[4];
    bf16x8 wzfr[4][8];
#pragma unroll
    for (int nt = 0; nt < 4; ++nt) {
        colg[nt] = wave * 64 + nt * 16 + ln;
        bpv[nt]  = bp[colg[nt]];
#pragma unroll
        for (int ks = 0; ks < 8; ++ks)
            wzfr[nt][ks] = ldfrag(WzG + colg[nt] * OUT_DIM + ks * 32 + q * 8);
    }
    __syncthreads();

    bf16x8 zfr[8];
#pragma unroll
    for (int ks = 0; ks < 8; ++ks)
        zfr[ks] = __builtin_bit_cast(bf16x8, *(const uint4*)&zS[ln][ks * 32 + q * 8]);

    const f32x4 zero4 = {0.f, 0.f, 0.f, 0.f};

    for (int t = 1; t <= MAX_ITER_N; ++t) {
        // z-update: two 4-deep partial chains per column tile
        f32x4 accA[4], accB[4];
#pragma unroll
        for (int nt = 0; nt < 4; ++nt) { accA[nt] = zero4; accB[nt] = zero4; }
#pragma unroll
        for (int ks = 0; ks < 4; ++ks)
#pragma unroll
            for (int nt = 0; nt < 4; ++nt) {
                accA[nt] = __builtin_amdgcn_mfma_f32_16x16x32_bf16(zfr[ks], wzfr[nt][ks], accA[nt], 0, 0, 0);
                accB[nt] = __builtin_amdgcn_mfma_f32_16x16x32_bf16(zfr[ks + 4], wzfr[nt][ks + 4], accB[nt], 0, 0, 0);
            }
        float vals[4][4];
#pragma unroll
        for (int nt = 0; nt < 4; ++nt)
#pragma unroll
            for (int i = 0; i < 4; ++i) {
                float v = accA[nt][i] + accB[nt][i] + bpv[nt];
                if (colg[nt] >= FREE_NUM_N) v = fmaxf(v, 0.0f);
                vals[nt][i] = v;
            }
        if (t == MAX_ITER_N) {
#pragma unroll
            for (int nt = 0; nt < 4; ++nt)
#pragma unroll
                for (int i = 0; i < 4; ++i)
                    out[(r0 + q * 4 + i) * OUT_DIM + colg[nt]] = vals[nt][i];
        }
        __syncthreads();   // S1: all waves done reading zS (z_{t-1})
#pragma unroll
        for (int nt = 0; nt < 4; ++nt)
#pragma unroll
            for (int i = 0; i < 4; ++i)
                zS[q * 4 + i][colg[nt]] = f2bf(vals[nt][i]);
        __syncthreads();   // S2: zS = z_t complete
#pragma unroll
        for (int ks = 0; ks < 8; ++ks)
            zfr[ks] = __builtin_bit_cast(bf16x8, *(const uint4*)&zS[ln][ks * 32 + q * 8]);

        // residual: per-wave shuffle-reduce -> LDS slot; no barrier, no atomic
        f32x4 r2A[2], r2B[2];
        r2A[0] = zero4; r2A[1] = zero4; r2B[0] = zero4; r2B[1] = zero4;
#pragma unroll
        for (int ks = 0; ks < 4; ++ks)
#pragma unroll
            for (int mt = 0; mt < 2; ++mt) {
                r2A[mt] = __builtin_amdgcn_mfma_f32_16x16x32_bf16(zfr[ks], afr[mt][ks], r2A[mt], 0, 0, 0);
                r2B[mt] = __builtin_amdgcn_mfma_f32_16x16x32_bf16(zfr[ks + 4], afr[mt][ks + 4], r2B[mt], 0, 0, 0);
            }
        float lmax = 0.0f;
#pragma unroll
        for (int mt = 0; mt < 2; ++mt)
#pragma unroll
            for (int i = 0; i < 4; ++i)
                lmax = fmaxf(lmax, fabsf(r2A[mt][i] + r2B[mt][i] - bvv[mt]));
#pragma unroll
        for (int off = 32; off > 0; off >>= 1)
            lmax = fmaxf(lmax, __shfl_xor(lmax, off));
        if (lane == 0) resS[t - 1][wave] = lmax;
    }

    // publish residuals once: 20 atomics per block, distinct addresses
    __syncthreads();
    if (tid < MAX_ITER_N) {
        float m = fmaxf(fmaxf(resS[tid][0], resS[tid][1]),
                        fmaxf(resS[tid][2], resS[tid][3]));
        atomicMax(res + tid, __float_as_uint(m));
    }

    grid_barrier(bar, 64);   // 64 blocks <= 256 CUs: co-residency guaranteed

    // decide (replay reference stopping rule) + cold fp32 fallback
    int T = MAX_ITER_N;
    for (int t = 0; t < MAX_ITER_N; ++t) {
        float r = __uint_as_float(res[t]);
        if (!(r > F_TOL_F)) { T = t + 1; break; }   // covers res<=tol and NaN
    }
    if (blockIdx.x == 0 && tid == 0)
        out[2 * BSZ * OUT_DIM] = (float)(T + 1);    // curr_iter

    if (T < MAX_ITER_N) {                           // cold path: exact fp32 recompute
        float (*zF)[257] = (float(*)[257])smem;
        const int row = tid >> 4;
        const int c0 = (tid & 15) * 16;
        __syncthreads();
        for (int i = 0; i < 16; ++i) zF[row][c0 + i] = outz[(r0 + row) * OUT_DIM + c0 + i];
        __syncthreads();
        const int j = tid;
        const float bj = bp[j];
        for (int t = 0; t < T; ++t) {
            float acc[16] = {};
            for (int k = 0; k < OUT_DIM; ++k) {
                float w = WzProj[j * OUT_DIM + k];
#pragma unroll
                for (int r = 0; r < 16; ++r) acc[r] += zF[r][k] * w;
            }
            __syncthreads();
#pragma unroll
            for (int r = 0; r < 16; ++r) {
                float v = acc[r] + bj;
                if (j >= FREE_NUM_N) v = fmaxf(v, 0.0f);
                zF[r][j] = v;
            }
            __syncthreads();
        }
        for (int i = 0; i < 16; ++i) out[(r0 + row) * OUT_DIM + c0 + i] = zF[row][c0 + i];
    }
}

extern "C" void kernel_launch(void* const* d_in, const int* in_sizes, int n_in,
                              void* d_out, int out_size, void* d_ws, size_t ws_size,
                              hipStream_t stream) {
    const float* b_primal = (const float*)d_in[0];
    const float* W0     = (const float*)d_in[1];
    const float* b0     = (const float*)d_in[2];
    const float* W1     = (const float*)d_in[3];
    const float* b1     = (const float*)d_in[4];
    const float* W2     = (const float*)d_in[5];
    const float* b2     = (const float*)d_in[6];
    const float* Amat   = (const float*)d_in[7];
    const float* b_vec  = (const float*)d_in[8];
    const float* WzProj = (const float*)d_in[9];
    const float* WbProj = (const float*)d_in[10];
    float* out = (float*)d_out;
    float* ws  = (float*)d_ws;

    hipLaunchKernelGGL(g1_k, dim3(1024), dim3(256), 0, stream,
                       b_primal, W0, b0, ws);
    hipLaunchKernelGGL(g2_k, dim3(1024 + 97), dim3(256), 0, stream,
                       W1, b1, WzProj, Amat, b_vec, WbProj, ws);
    hipLaunchKernelGGL(g3_k, dim3(256), dim3(256), 0, stream,
                       W2, b2, out, ws);
    hipLaunchKernelGGL(loop_k, dim3(64), dim3(256), 0, stream,
                       b_vec, WzProj, out, ws);
}